// Round 5
// baseline (7491.227 us; speedup 1.0000x reference)
//
#include <hip/hip_runtime.h>
#include <hip/hip_bf16.h>

typedef _Float16 f16;
typedef _Float16 f16x2 __attribute__((ext_vector_type(2)));
typedef _Float16 f16x4 __attribute__((ext_vector_type(4)));
typedef _Float16 f16x8 __attribute__((ext_vector_type(8)));

#define BATCH 128
#define SEQ   1024
#define IND   256
#define HID   512

#if defined(__has_builtin)
#if __has_builtin(__builtin_amdgcn_fdot2)
#define HAVE_FDOT2 1
#endif
#endif

__device__ __forceinline__ float fdot2(f16x2 a, f16x2 b, float c) {
#ifdef HAVE_FDOT2
  return __builtin_amdgcn_fdot2(a, b, c, false);
#else
  return c + (float)a[0] * (float)b[0] + (float)a[1] * (float)b[1];
#endif
}

union v8u {
  f16x8 v;
  f16x2 h[4];
};

__device__ __forceinline__ float tanh_fast(float s) {
  float e = __expf(2.0f * s);
  return 1.0f - 2.0f / (e + 1.0f);
}

// ---------------------------------------------------------------------------
// prep: W_su f32 [768][512] -> WzT f16 [h=512][k=512], WxT f16 [h=512][d=256]
// block 0 also zeroes the cross-CU sync flags (fresh every launch).
// ---------------------------------------------------------------------------
__global__ __launch_bounds__(256) void prep_kernel(const float* __restrict__ Wsu,
                                                   f16* __restrict__ WzT,
                                                   f16* __restrict__ WxT,
                                                   int* __restrict__ flags) {
  if (blockIdx.x == 0 && threadIdx.x < 256) flags[threadIdx.x] = 0;
  int g = blockIdx.x * 256 + threadIdx.x;  // 0 .. 768*512-1
  int k = g >> 9;
  int h = g & 511;
  float v = Wsu[g];
  if (k < HID) WzT[h * HID + k] = (f16)v;
  else         WxT[h * IND + (k - HID)] = (f16)v;
}

// ---------------------------------------------------------------------------
// gemm1: xw[m][n] = sum_k x[m][k] * WxT[n][k] + bsu[n]   (f16 dot2, 64x64 tile)
// ---------------------------------------------------------------------------
__global__ __launch_bounds__(256) void gemm1_kernel(const float* __restrict__ x,
                                                    const f16* __restrict__ WxT,
                                                    const float* __restrict__ bsu,
                                                    f16* __restrict__ xw) {
  __shared__ __align__(16) f16x2 X2[16][64];  // [k-pair][row]
  __shared__ __align__(16) f16x2 W2[16][64];  // [k-pair][col]
  int m0 = blockIdx.x * 64, n0 = blockIdx.y * 64;
  int tid = threadIdx.x;
  int cg = tid & 15;
  int rg = tid >> 4;
  int sr = tid >> 2;
  int q  = tid & 3;

  float4 bv = *(const float4*)&bsu[n0 + cg * 4];
  float bj[4] = {bv.x, bv.y, bv.z, bv.w};
  float acc[4][4];
#pragma unroll
  for (int i = 0; i < 4; ++i)
#pragma unroll
    for (int j = 0; j < 4; ++j) acc[i][j] = bj[j];

  for (int ks = 0; ks < 8; ++ks) {
    int k0 = ks * 32;
    const float4* xp = (const float4*)&x[(m0 + sr) * IND + k0 + q * 8];
    float4 a0 = xp[0], a1 = xp[1];
    X2[q * 4 + 0][sr] = (f16x2){(f16)a0.x, (f16)a0.y};
    X2[q * 4 + 1][sr] = (f16x2){(f16)a0.z, (f16)a0.w};
    X2[q * 4 + 2][sr] = (f16x2){(f16)a1.x, (f16)a1.y};
    X2[q * 4 + 3][sr] = (f16x2){(f16)a1.z, (f16)a1.w};
    v8u wv;
    wv.v = *(const f16x8*)&WxT[(n0 + sr) * IND + k0 + q * 8];
#pragma unroll
    for (int p = 0; p < 4; ++p) W2[q * 4 + p][sr] = wv.h[p];
    __syncthreads();
#pragma unroll
    for (int kk = 0; kk < 16; ++kk) {
      v8u xv, wvv;
      xv.v = *(const f16x8*)&X2[kk][rg * 4];
      wvv.v = *(const f16x8*)&W2[kk][cg * 4];
#pragma unroll
      for (int i = 0; i < 4; ++i) {
        f16x2 xi = xv.h[i];
#pragma unroll
        for (int j = 0; j < 4; ++j) {
          acc[i][j] = fdot2(xi, wvv.h[j], acc[i][j]);
        }
      }
    }
    __syncthreads();
  }
#pragma unroll
  for (int i = 0; i < 4; ++i) {
    int row = m0 + rg * 4 + i;
    f16x4 o = {(f16)acc[i][0], (f16)acc[i][1], (f16)acc[i][2], (f16)acc[i][3]};
    *(f16x4*)&xw[row * HID + n0 + cg * 4] = o;
  }
}

// ---------------------------------------------------------------------------
// scan2: 256 blocks (cooperative) x 1024 threads. Blocks (b, b+128) form a
// pair handling batch b: block b -> h[0:256), block b+128 -> h[256:512).
// thread (w=tid>>6, l=tid&63): kc=l>>3 (64-k chunk), rows H,H+1 where
// H = half*256 + w*16 + (l&7)*2. Weights FULLY register-resident (64 VGPR).
// Per step: dots -> shfl_xor butterfly over kc lanes -> tanh (l<8) ->
// half-z exchange via agent-scope atomics (parity dbuf + monotonic flags).
// ---------------------------------------------------------------------------
__global__ __launch_bounds__(1024, 4) void scan2_kernel(
    const f16* __restrict__ WzT, const f16* __restrict__ xw,
    const float* __restrict__ carry, const float* __restrict__ Wout,
    const float* __restrict__ bout, float* __restrict__ outp,
    unsigned long long* zx64, int* flags) {
  __shared__ __align__(16) f16 zsh[512];            // full z, swizzled
  __shared__ __align__(16) unsigned long long zmine8[64];  // my half, packed
  __shared__ float red[512];

  const int bid = blockIdx.x;
  const int half = bid >> 7;
  const int b = bid & 127;
  const int partner = bid ^ 128;
  const int tid = threadIdx.x;
  const int w = tid >> 6, l = tid & 63;
  const int kc = l >> 3;
  const int hloc = w * 16 + (l & 7) * 2;
  const int H = half * 256 + hloc;
  const int k0 = kc * 64;

  // weights for rows H, H+1, k-chunk [k0,k0+64) -> 64 VGPRs
  f16x2 wreg[2][32];
#pragma unroll
  for (int j = 0; j < 2; ++j) {
    const f16* wp = &WzT[(H + j) * HID + k0];
#pragma unroll
    for (int s = 0; s < 8; ++s) {
      v8u v;
      v.v = *(const f16x8*)&wp[s * 8];
#pragma unroll
      for (int p = 0; p < 4; ++p) wreg[j][s * 4 + p] = v.h[p];
    }
  }
#pragma unroll
  for (int j = 0; j < 2; ++j) {
#pragma unroll
    for (int s = 0; s < 32; ++s) {
      unsigned u = __builtin_bit_cast(unsigned, wreg[j][s]);
      asm volatile("" : "+v"(u));
      wreg[j][s] = __builtin_bit_cast(f16x2, u);
    }
  }

  // init full z^0 from carry (swizzled)
  if (tid < HID) {
    float z0 = carry[b * HID + tid];
    int c = tid >> 6, q = (tid >> 3) & 7, off = tid & 7;
    zsh[c * 64 + ((q ^ c) & 7) * 8 + off] = (f16)z0;
  }

  // loop-invariant own-z write slot (swizzled)
  const int cH = H >> 6, qH = (H >> 3) & 7, offH = H & 7;
  f16x2* const zown = (f16x2*)&zsh[cH * 64 + ((qH ^ cH) & 7) * 8 + offH];

  f16x2 xw_cur = {};
  if (l < 8) xw_cur = *(const f16x2*)&xw[(size_t)b * SEQ * HID + H];

  __syncthreads();

  float z0f = 0.f, z1f = 0.f;
  for (int i = 0; i < SEQ; ++i) {
    f16x2 xw_nxt = xw_cur;
    if (l < 8) {
      int tn = (i + 1 < SEQ) ? i + 1 : i;
      xw_nxt = *(const f16x2*)&xw[((size_t)b * SEQ + tn) * HID + H];
    }

    float a0 = 0.f, a1 = 0.f;
#pragma unroll
    for (int s = 0; s < 8; ++s) {
      v8u zc;
      zc.v = *(const f16x8*)&zsh[k0 + ((s ^ kc) & 7) * 8];
#pragma unroll
      for (int p = 0; p < 4; ++p) {
        a0 = fdot2(zc.h[p], wreg[0][s * 4 + p], a0);
        a1 = fdot2(zc.h[p], wreg[1][s * 4 + p], a1);
      }
    }
    // butterfly sum over kc lanes (lane bits 3,4,5)
    a0 += __shfl_xor(a0, 8);  a1 += __shfl_xor(a1, 8);
    a0 += __shfl_xor(a0, 16); a1 += __shfl_xor(a1, 16);
    a0 += __shfl_xor(a0, 32); a1 += __shfl_xor(a1, 32);

    f16x2 zpk = {};
    if (l < 8) {
      z0f = tanh_fast(a0 + (float)xw_cur[0]);
      z1f = tanh_fast(a1 + (float)xw_cur[1]);
      zpk[0] = (f16)z0f;
      zpk[1] = (f16)z1f;
      ((f16x2*)zmine8)[hloc >> 1] = zpk;
    }
    __syncthreads();  // (A) dot-reads done, zmine complete
    if (l < 8) *zown = zpk;
    if (w == 0) {
      unsigned long long v = zmine8[l];
      __hip_atomic_store(&zx64[(size_t)bid * 128 + (size_t)(i & 1) * 64 + l], v,
                         __ATOMIC_RELAXED, __HIP_MEMORY_SCOPE_AGENT);
      if (l == 0)
        __hip_atomic_store(&flags[bid], i + 1, __ATOMIC_RELEASE,
                           __HIP_MEMORY_SCOPE_AGENT);
      while (__hip_atomic_load(&flags[partner], __ATOMIC_ACQUIRE,
                               __HIP_MEMORY_SCOPE_AGENT) < i + 1) {}
      unsigned long long pv = __hip_atomic_load(
          &zx64[(size_t)partner * 128 + (size_t)(i & 1) * 64 + l],
          __ATOMIC_RELAXED, __HIP_MEMORY_SCOPE_AGENT);
      int Hp = ((half ^ 1) << 8) + l * 4;
      int cp = Hp >> 6, qp = (Hp >> 3) & 7, offp = Hp & 7;
      *(unsigned long long*)&zsh[cp * 64 + ((qp ^ cp) & 7) * 8 + offp] = pv;
    }
    __syncthreads();  // (B) zsh holds full z^{i+1}
    xw_cur = xw_nxt;
  }

  // z_last (f32 exact from registers)
  if (l < 8) {
    float2 o = {z0f, z1f};
    *(float2*)&outp[BATCH + (size_t)b * HID + H] = o;
  }

  // out[b] computed by half-0 block from the (exchanged) full zsh
  if (half == 0) {
    if (tid < HID) {
      int c = tid >> 6, q = (tid >> 3) & 7, off = tid & 7;
      red[tid] = (float)zsh[c * 64 + ((q ^ c) & 7) * 8 + off] * Wout[tid];
    }
    __syncthreads();
    if (tid < 64) {
      float s2 = 0.f;
#pragma unroll
      for (int ii = 0; ii < 8; ++ii) s2 += red[tid + 64 * ii];
      red[tid] = s2;
    }
    if (tid == 0) {
      float s3 = 0.f;
      for (int ii = 0; ii < 64; ++ii) s3 += red[ii];
      outp[b] = s3 + bout[0];
    }
  }
}

// ---------------------------------------------------------------------------
extern "C" void kernel_launch(void* const* d_in, const int* in_sizes, int n_in,
                              void* d_out, int out_size, void* d_ws, size_t ws_size,
                              hipStream_t stream) {
  const float* x     = (const float*)d_in[0];
  const float* carry = (const float*)d_in[1];
  const float* Wsu   = (const float*)d_in[2];
  const float* bsu   = (const float*)d_in[3];
  const float* Wout  = (const float*)d_in[4];
  const float* bout  = (const float*)d_in[5];
  float* outp = (float*)d_out;

  char* ws = (char*)d_ws;
  f16* WzT = (f16*)(ws);                                   // 512 KB
  f16* WxT = (f16*)(ws + 512 * 1024);                      // 256 KB
  f16* xw  = (f16*)(ws + 768 * 1024);                      // 128 MB
  size_t xw_bytes = (size_t)BATCH * SEQ * HID * sizeof(f16);
  unsigned long long* zx64 = (unsigned long long*)(ws + 768 * 1024 + xw_bytes);  // 256 KB
  int* flags = (int*)(ws + 768 * 1024 + xw_bytes + 256 * 1024);                  // 1 KB

  prep_kernel<<<dim3((768 * 512) / 256), 256, 0, stream>>>(Wsu, WzT, WxT, flags);
  gemm1_kernel<<<dim3(BATCH * SEQ / 64, HID / 64), 256, 0, stream>>>(x, WxT, bsu, xw);

  void* args[] = {(void*)&WzT, (void*)&xw, (void*)&carry, (void*)&Wout,
                  (void*)&bout, (void*)&outp, (void*)&zx64, (void*)&flags};
  hipLaunchCooperativeKernel((const void*)scan2_kernel, dim3(256), dim3(1024),
                             args, 0, stream);
}

// Round 6
// 2598.362 us; speedup vs baseline: 2.8831x; 2.8831x over previous
//
#include <hip/hip_runtime.h>
#include <hip/hip_bf16.h>

typedef _Float16 f16;
typedef _Float16 f16x2 __attribute__((ext_vector_type(2)));
typedef _Float16 f16x4 __attribute__((ext_vector_type(4)));
typedef _Float16 f16x8 __attribute__((ext_vector_type(8)));

#define BATCH 128
#define SEQ   1024
#define IND   256
#define HID   512

#if defined(__has_builtin)
#if __has_builtin(__builtin_amdgcn_fdot2)
#define HAVE_FDOT2 1
#endif
#endif

__device__ __forceinline__ float fdot2(f16x2 a, f16x2 b, float c) {
#ifdef HAVE_FDOT2
  return __builtin_amdgcn_fdot2(a, b, c, false);
#else
  return c + (float)a[0] * (float)b[0] + (float)a[1] * (float)b[1];
#endif
}

union v8u {
  f16x8 v;
  f16x2 h[4];
};

__device__ __forceinline__ float tanh_fast(float s) {
  float e = __expf(2.0f * s);
  return 1.0f - 2.0f / (e + 1.0f);
}

// ---------------------------------------------------------------------------
// prep: W_su f32 [768][512] -> WzT f16 [h=512][k=512], WxT f16 [h=512][d=256]
// ---------------------------------------------------------------------------
__global__ __launch_bounds__(256) void prep_kernel(const float* __restrict__ Wsu,
                                                   f16* __restrict__ WzT,
                                                   f16* __restrict__ WxT) {
  int g = blockIdx.x * 256 + threadIdx.x;  // 0 .. 768*512-1
  int k = g >> 9;
  int h = g & 511;
  float v = Wsu[g];
  if (k < HID) WzT[h * HID + k] = (f16)v;
  else         WxT[h * IND + (k - HID)] = (f16)v;
}

// ---------------------------------------------------------------------------
// gemm1: xw[m][n] = sum_k x[m][k] * WxT[n][k] + bsu[n]   (f16 dot2, 64x64 tile)
// ---------------------------------------------------------------------------
__global__ __launch_bounds__(256) void gemm1_kernel(const float* __restrict__ x,
                                                    const f16* __restrict__ WxT,
                                                    const float* __restrict__ bsu,
                                                    f16* __restrict__ xw) {
  __shared__ __align__(16) f16x2 X2[16][64];  // [k-pair][row]
  __shared__ __align__(16) f16x2 W2[16][64];  // [k-pair][col]
  int m0 = blockIdx.x * 64, n0 = blockIdx.y * 64;
  int tid = threadIdx.x;
  int cg = tid & 15;
  int rg = tid >> 4;
  int sr = tid >> 2;
  int q  = tid & 3;

  float4 bv = *(const float4*)&bsu[n0 + cg * 4];
  float bj[4] = {bv.x, bv.y, bv.z, bv.w};
  float acc[4][4];
#pragma unroll
  for (int i = 0; i < 4; ++i)
#pragma unroll
    for (int j = 0; j < 4; ++j) acc[i][j] = bj[j];

  for (int ks = 0; ks < 8; ++ks) {
    int k0 = ks * 32;
    const float4* xp = (const float4*)&x[(m0 + sr) * IND + k0 + q * 8];
    float4 a0 = xp[0], a1 = xp[1];
    X2[q * 4 + 0][sr] = (f16x2){(f16)a0.x, (f16)a0.y};
    X2[q * 4 + 1][sr] = (f16x2){(f16)a0.z, (f16)a0.w};
    X2[q * 4 + 2][sr] = (f16x2){(f16)a1.x, (f16)a1.y};
    X2[q * 4 + 3][sr] = (f16x2){(f16)a1.z, (f16)a1.w};
    v8u wv;
    wv.v = *(const f16x8*)&WxT[(n0 + sr) * IND + k0 + q * 8];
#pragma unroll
    for (int p = 0; p < 4; ++p) W2[q * 4 + p][sr] = wv.h[p];
    __syncthreads();
#pragma unroll
    for (int kk = 0; kk < 16; ++kk) {
      v8u xv, wvv;
      xv.v = *(const f16x8*)&X2[kk][rg * 4];
      wvv.v = *(const f16x8*)&W2[kk][cg * 4];
#pragma unroll
      for (int i = 0; i < 4; ++i) {
        f16x2 xi = xv.h[i];
#pragma unroll
        for (int j = 0; j < 4; ++j) {
          acc[i][j] = fdot2(xi, wvv.h[j], acc[i][j]);
        }
      }
    }
    __syncthreads();
  }
#pragma unroll
  for (int i = 0; i < 4; ++i) {
    int row = m0 + rg * 4 + i;
    f16x4 o = {(f16)acc[i][0], (f16)acc[i][1], (f16)acc[i][2], (f16)acc[i][3]};
    *(f16x4*)&xw[row * HID + n0 + cg * 4] = o;
  }
}

// ---------------------------------------------------------------------------
// scan: 128 blocks (1 batch) x 1024 threads (16 waves, 4/SIMD, 1 block/CU).
// Lane map: w=tid>>6, l=tid&63, kc=l&7 (64-k chunk), hq=l>>3,
// hbase=w*32+hq*4. Thread owns rows hbase..hbase+3 x k-chunk [kc*64,+64).
// Rows 0..2 register-resident (96 VGPR); row 3 streamed from LDS wl[s][tid].
// Per step: 8x(zsh b128 bcast + wl b128) -> 128 fdot2 -> shfl_xor(1,2,4)
// butterfly over kc -> tanh on kc<4 lanes -> write z to zsh[p^1] -> ONE
// barrier. zsh double-buffered; XOR swizzle keeps reads conflict-free.
// ---------------------------------------------------------------------------
__global__ __launch_bounds__(1024, 4) void scan_kernel(
    const f16* __restrict__ WzT, const f16* __restrict__ xw,
    const float* __restrict__ carry, const float* __restrict__ Wout,
    const float* __restrict__ bout, float* __restrict__ outp) {
  __shared__ __align__(16) f16 zsh[2][512];        // 2 KB, double-buffered z
  __shared__ __align__(16) f16x8 wl[8][1024];      // 128 KB: row-3 weights
  __shared__ float red[512];                       // 2 KB epilogue

  const int b = blockIdx.x;
  const int tid = threadIdx.x;
  const int w = tid >> 6, l = tid & 63;
  const int kc = l & 7;       // lane bits 0..2: k-chunk  (butterfly axis)
  const int hq = l >> 3;      // lane bits 3..5: row group
  const int hbase = w * 32 + hq * 4;
  const int k0 = kc * 64;

  // rows hbase..hbase+2 -> registers (96 VGPRs)
  f16x2 wreg[3][32];
#pragma unroll
  for (int j = 0; j < 3; ++j) {
    const f16* wp = &WzT[(hbase + j) * HID + k0];
#pragma unroll
    for (int s = 0; s < 8; ++s) {
      v8u v;
      v.v = *(const f16x8*)&wp[s * 8];
#pragma unroll
      for (int p = 0; p < 4; ++p) wreg[j][s * 4 + p] = v.h[p];
    }
  }
  // opacity pin: no remat of the register-resident rows
#pragma unroll
  for (int j = 0; j < 3; ++j) {
#pragma unroll
    for (int s = 0; s < 32; ++s) {
      unsigned u = __builtin_bit_cast(unsigned, wreg[j][s]);
      asm volatile("" : "+v"(u));
      wreg[j][s] = __builtin_bit_cast(f16x2, u);
    }
  }
  // row hbase+3 -> LDS, [s][tid]: a wave's read of slice s is contiguous 1KB
  {
    const f16* wp3 = &WzT[(hbase + 3) * HID + k0];
#pragma unroll
    for (int s = 0; s < 8; ++s) wl[s][tid] = *(const f16x8*)&wp3[s * 8];
  }

  // z^0 from carry into buffer 0 (swizzled: h -> c*64 + ((q^c)&7)*8 + off)
  if (tid < HID) {
    float z0 = carry[b * HID + tid];
    int c = tid >> 6, q = (tid >> 3) & 7, off = tid & 7;
    zsh[0][c * 64 + ((q ^ c) & 7) * 8 + off] = (f16)z0;
  }

  // per-lane fixed output row h = hbase + kc (kc<4 lanes are writers)
  const int myh = hbase + kc;
  const int cW = myh >> 6, qW = (myh >> 3) & 7, offW = myh & 7;
  const int wslot = cW * 64 + ((qW ^ cW) & 7) * 8 + offW;
  const bool wlane = (kc < 4);

  float xw_cur = 0.f;
  if (wlane) xw_cur = (float)xw[(size_t)b * SEQ * HID + myh];

  __syncthreads();

  float zlast = 0.f;
  for (int t = 0; t < SEQ; ++t) {
    const int p = t & 1;
    // prefetch next xw (latency hides under the dot phase)
    float xw_nxt = xw_cur;
    if (wlane) {
      int tn = (t + 1 < SEQ) ? t + 1 : t;
      xw_nxt = (float)xw[((size_t)b * SEQ + tn) * HID + myh];
    }

    const f16* zb = &zsh[p][k0];
    float a0 = 0.f, a1 = 0.f, a2 = 0.f, a3 = 0.f;
#pragma unroll
    for (int s = 0; s < 8; ++s) {
      v8u zc, wv;
      zc.v = *(const f16x8*)&zb[((s ^ kc) & 7) * 8];  // subchunk s (swizzled)
      wv.v = wl[s][tid];
#pragma unroll
      for (int q4 = 0; q4 < 4; ++q4) {
        f16x2 zp = zc.h[q4];
        int pi = s * 4 + q4;
        a0 = fdot2(zp, wreg[0][pi], a0);
        a1 = fdot2(zp, wreg[1][pi], a1);
        a2 = fdot2(zp, wreg[2][pi], a2);
        a3 = fdot2(zp, wv.h[q4], a3);
      }
    }
    // butterfly over kc (lane bits 0..2)
    a0 += __shfl_xor(a0, 1); a1 += __shfl_xor(a1, 1);
    a2 += __shfl_xor(a2, 1); a3 += __shfl_xor(a3, 1);
    a0 += __shfl_xor(a0, 2); a1 += __shfl_xor(a1, 2);
    a2 += __shfl_xor(a2, 2); a3 += __shfl_xor(a3, 2);
    a0 += __shfl_xor(a0, 4); a1 += __shfl_xor(a1, 4);
    a2 += __shfl_xor(a2, 4); a3 += __shfl_xor(a3, 4);

    if (wlane) {
      float av = (kc == 0) ? a0 : (kc == 1) ? a1 : (kc == 2) ? a2 : a3;
      float z = tanh_fast(av + xw_cur);
      zlast = z;
      zsh[p ^ 1][wslot] = (f16)z;
    }
    __syncthreads();
    xw_cur = xw_nxt;
  }

  // outputs: z_last (f32, exact from register) + out[b] GEMV
  if (wlane) {
    outp[BATCH + (size_t)b * HID + myh] = zlast;
    red[myh] = zlast * Wout[myh];
  }
  __syncthreads();
  if (tid < 64) {
    float s2 = 0.f;
#pragma unroll
    for (int i = 0; i < 8; ++i) s2 += red[tid + 64 * i];
    red[tid] = s2;
  }
  __syncthreads();
  if (tid == 0) {
    float s3 = 0.f;
    for (int i = 0; i < 64; ++i) s3 += red[i];
    outp[b] = s3 + bout[0];
  }
}

// ---------------------------------------------------------------------------
extern "C" void kernel_launch(void* const* d_in, const int* in_sizes, int n_in,
                              void* d_out, int out_size, void* d_ws, size_t ws_size,
                              hipStream_t stream) {
  const float* x     = (const float*)d_in[0];
  const float* carry = (const float*)d_in[1];
  const float* Wsu   = (const float*)d_in[2];
  const float* bsu   = (const float*)d_in[3];
  const float* Wout  = (const float*)d_in[4];
  const float* bout  = (const float*)d_in[5];
  float* outp = (float*)d_out;

  char* ws = (char*)d_ws;
  f16* WzT = (f16*)(ws);                        // 512 KB
  f16* WxT = (f16*)(ws + 512 * 1024);           // 256 KB
  f16* xw  = (f16*)(ws + 768 * 1024);           // 128 MB (131072*512*2B)

  prep_kernel<<<dim3((768 * 512) / 256), 256, 0, stream>>>(Wsu, WzT, WxT);
  gemm1_kernel<<<dim3(BATCH * SEQ / 64, HID / 64), 256, 0, stream>>>(x, WxT, bsu, xw);
  scan_kernel<<<dim3(BATCH), 1024, 0, stream>>>(WzT, xw, carry, Wout, bout, outp);
}

// Round 7
// 2177.793 us; speedup vs baseline: 3.4398x; 1.1931x over previous
//
#include <hip/hip_runtime.h>
#include <hip/hip_bf16.h>

typedef _Float16 f16;
typedef _Float16 f16x2 __attribute__((ext_vector_type(2)));
typedef _Float16 f16x4 __attribute__((ext_vector_type(4)));
typedef _Float16 f16x8 __attribute__((ext_vector_type(8)));

#define BATCH 128
#define SEQ   1024
#define IND   256
#define HID   512

#if defined(__has_builtin)
#if __has_builtin(__builtin_amdgcn_fdot2)
#define HAVE_FDOT2 1
#endif
#endif

__device__ __forceinline__ float fdot2(f16x2 a, f16x2 b, float c) {
#ifdef HAVE_FDOT2
  return __builtin_amdgcn_fdot2(a, b, c, false);
#else
  return c + (float)a[0] * (float)b[0] + (float)a[1] * (float)b[1];
#endif
}

union v8u {
  f16x8 v;
  f16x2 h[4];
  int   i[4];
};

__device__ __forceinline__ float tanh_fast(float s) {
  float e = __expf(2.0f * s);
  return 1.0f - 2.0f / (e + 1.0f);
}

// rotate a 16B z-fragment across lanes with a symmetric XOR DPP pattern
template <int CTRL>
__device__ __forceinline__ void rot_dpp(v8u& z) {
#pragma unroll
  for (int d = 0; d < 4; ++d)
    z.i[d] = __builtin_amdgcn_mov_dpp(z.i[d], CTRL, 0xf, 0xf, false);
}

// ---------------------------------------------------------------------------
// prep: W_su f32 [768][512] -> WzT f16 [h=512][k=512], WxT f16 [h=512][d=256]
// ---------------------------------------------------------------------------
__global__ __launch_bounds__(256) void prep_kernel(const float* __restrict__ Wsu,
                                                   f16* __restrict__ WzT,
                                                   f16* __restrict__ WxT) {
  int g = blockIdx.x * 256 + threadIdx.x;  // 0 .. 768*512-1
  int k = g >> 9;
  int h = g & 511;
  float v = Wsu[g];
  if (k < HID) WzT[h * HID + k] = (f16)v;
  else         WxT[h * IND + (k - HID)] = (f16)v;
}

// ---------------------------------------------------------------------------
// gemm1: xw[m][n] = sum_k x[m][k] * WxT[n][k] + bsu[n]   (f16 dot2, 64x64 tile)
// ---------------------------------------------------------------------------
__global__ __launch_bounds__(256) void gemm1_kernel(const float* __restrict__ x,
                                                    const f16* __restrict__ WxT,
                                                    const float* __restrict__ bsu,
                                                    f16* __restrict__ xw) {
  __shared__ __align__(16) f16x2 X2[16][64];  // [k-pair][row]
  __shared__ __align__(16) f16x2 W2[16][64];  // [k-pair][col]
  int m0 = blockIdx.x * 64, n0 = blockIdx.y * 64;
  int tid = threadIdx.x;
  int cg = tid & 15;
  int rg = tid >> 4;
  int sr = tid >> 2;
  int q  = tid & 3;

  float4 bv = *(const float4*)&bsu[n0 + cg * 4];
  float bj[4] = {bv.x, bv.y, bv.z, bv.w};
  float acc[4][4];
#pragma unroll
  for (int i = 0; i < 4; ++i)
#pragma unroll
    for (int j = 0; j < 4; ++j) acc[i][j] = bj[j];

  for (int ks = 0; ks < 8; ++ks) {
    int k0 = ks * 32;
    const float4* xp = (const float4*)&x[(m0 + sr) * IND + k0 + q * 8];
    float4 a0 = xp[0], a1 = xp[1];
    X2[q * 4 + 0][sr] = (f16x2){(f16)a0.x, (f16)a0.y};
    X2[q * 4 + 1][sr] = (f16x2){(f16)a0.z, (f16)a0.w};
    X2[q * 4 + 2][sr] = (f16x2){(f16)a1.x, (f16)a1.y};
    X2[q * 4 + 3][sr] = (f16x2){(f16)a1.z, (f16)a1.w};
    v8u wv;
    wv.v = *(const f16x8*)&WxT[(n0 + sr) * IND + k0 + q * 8];
#pragma unroll
    for (int p = 0; p < 4; ++p) W2[q * 4 + p][sr] = wv.h[p];
    __syncthreads();
#pragma unroll
    for (int kk = 0; kk < 16; ++kk) {
      v8u xv, wvv;
      xv.v = *(const f16x8*)&X2[kk][rg * 4];
      wvv.v = *(const f16x8*)&W2[kk][cg * 4];
#pragma unroll
      for (int i = 0; i < 4; ++i) {
        f16x2 xi = xv.h[i];
#pragma unroll
        for (int j = 0; j < 4; ++j) {
          acc[i][j] = fdot2(xi, wvv.h[j], acc[i][j]);
        }
      }
    }
    __syncthreads();
  }
#pragma unroll
  for (int i = 0; i < 4; ++i) {
    int row = m0 + rg * 4 + i;
    f16x4 o = {(f16)acc[i][0], (f16)acc[i][1], (f16)acc[i][2], (f16)acc[i][3]};
    *(f16x4*)&xw[row * HID + n0 + cg * 4] = o;
  }
}

// ---------------------------------------------------------------------------
// scan v3: 128 blocks (1 batch) x 1024 threads (16 waves, 1 block/CU).
// Lane map: w=tid>>6, l=tid&63; group g=l>>3 owns k-chunk [g*64,g*64+64);
// lane b=l&7 owns rows hbase=w*32+b*4 .. +3.
// z distribution: each lane does ONE ds_read_b128 (its 16B slice of the
// group's chunk), then the fragment rotates through the 8-lane group via
// symmetric XOR DPP (xor1=quad_perm 0xB1, xor3=0x1B, xor7=half_mirror 0x141;
// sequence 1,3,1,7,1,3,1 => lane holds slice (b^s) at iter s).
// Weights: rows 0..2 register-resident (96 VGPR, pre-permuted by (s^b));
// row 3 streamed from LDS wl[s][tid] (pre-permuted at init).
// Reduction over chunks via part[8][512] + finisher split + shfl_xor(32).
// ---------------------------------------------------------------------------
__global__ __launch_bounds__(1024, 4) void scan_kernel(
    const f16* __restrict__ WzT, const f16* __restrict__ xw,
    const float* __restrict__ carry, const float* __restrict__ Wout,
    const float* __restrict__ bout, float* __restrict__ outp) {
  __shared__ __align__(16) f16 zsh[512];           // 1 KB, single buffer
  __shared__ __align__(16) f16x8 wl[8][1024];      // 128 KB: row-3 weights
  __shared__ __align__(16) float part[8][512];     // 16 KB
  __shared__ float red[512];                       // 2 KB epilogue

  const int b_ = blockIdx.x;
  const int tid = threadIdx.x;
  const int w = tid >> 6, l = tid & 63;
  const int g  = l >> 3;      // chunk index (kc)
  const int bb = l & 7;       // slice phase / row-quad selector
  const int hbase = w * 32 + bb * 4;

  // rows hbase..hbase+2 -> registers, slice-permuted by (s^bb)
  f16x2 wreg[3][32];
#pragma unroll
  for (int r = 0; r < 3; ++r) {
#pragma unroll
    for (int s = 0; s < 8; ++s) {
      v8u v;
      v.v = *(const f16x8*)&WzT[(hbase + r) * HID + g * 64 + ((s ^ bb) & 7) * 8];
#pragma unroll
      for (int p = 0; p < 4; ++p) wreg[r][s * 4 + p] = v.h[p];
    }
  }
  // opacity pin: prevent remat/sinking of register-resident rows
#pragma unroll
  for (int r = 0; r < 3; ++r) {
#pragma unroll
    for (int s = 0; s < 32; ++s) {
      unsigned u = __builtin_bit_cast(unsigned, wreg[r][s]);
      asm volatile("" : "+v"(u));
      wreg[r][s] = __builtin_bit_cast(f16x2, u);
    }
  }
  // row hbase+3 -> LDS, consumption order (slice-permuted)
#pragma unroll
  for (int s = 0; s < 8; ++s)
    wl[s][tid] = *(const f16x8*)&WzT[(hbase + 3) * HID + g * 64 + ((s ^ bb) & 7) * 8];

  // z^0 from carry, plain layout z[h]
  if (tid < HID) zsh[tid] = (f16)carry[b_ * HID + tid];

  const int fl = l & 31, half = l >> 5;
  const int myh = w * 32 + fl;
  const bool wlane = (half == 0);
  float xw_cur = 0.f;
  if (wlane) xw_cur = (float)xw[(size_t)b_ * SEQ * HID + myh];

  __syncthreads();

  float zlast = 0.f;
  for (int t = 0; t < SEQ; ++t) {
    float xw_nxt = xw_cur;
    if (wlane) {
      int tn = (t + 1 < SEQ) ? t + 1 : t;
      xw_nxt = (float)xw[((size_t)b_ * SEQ + tn) * HID + myh];
    }

    // ONE cooperative z load: my 16B slice of my group's chunk
    v8u zc;
    zc.v = *(const f16x8*)&zsh[g * 64 + bb * 8];

    float a0 = 0.f, a1 = 0.f, a2 = 0.f, a3 = 0.f;
#define DOT_SLICE(S)                                                  \
    {                                                                 \
      v8u wv;                                                         \
      wv.v = wl[S][tid];                                              \
      a0 = fdot2(zc.h[0], wreg[0][S * 4 + 0], a0);                    \
      a1 = fdot2(zc.h[0], wreg[1][S * 4 + 0], a1);                    \
      a2 = fdot2(zc.h[0], wreg[2][S * 4 + 0], a2);                    \
      a3 = fdot2(zc.h[0], wv.h[0], a3);                               \
      a0 = fdot2(zc.h[1], wreg[0][S * 4 + 1], a0);                    \
      a1 = fdot2(zc.h[1], wreg[1][S * 4 + 1], a1);                    \
      a2 = fdot2(zc.h[1], wreg[2][S * 4 + 1], a2);                    \
      a3 = fdot2(zc.h[1], wv.h[1], a3);                               \
      a0 = fdot2(zc.h[2], wreg[0][S * 4 + 2], a0);                    \
      a1 = fdot2(zc.h[2], wreg[1][S * 4 + 2], a1);                    \
      a2 = fdot2(zc.h[2], wreg[2][S * 4 + 2], a2);                    \
      a3 = fdot2(zc.h[2], wv.h[2], a3);                               \
      a0 = fdot2(zc.h[3], wreg[0][S * 4 + 3], a0);                    \
      a1 = fdot2(zc.h[3], wreg[1][S * 4 + 3], a1);                    \
      a2 = fdot2(zc.h[3], wreg[2][S * 4 + 3], a2);                    \
      a3 = fdot2(zc.h[3], wv.h[3], a3);                               \
    }
    DOT_SLICE(0) rot_dpp<0xB1>(zc);   // xor1
    DOT_SLICE(1) rot_dpp<0x1B>(zc);   // xor3
    DOT_SLICE(2) rot_dpp<0xB1>(zc);   // xor1
    DOT_SLICE(3) rot_dpp<0x141>(zc);  // xor7 (half mirror)
    DOT_SLICE(4) rot_dpp<0xB1>(zc);   // xor1
    DOT_SLICE(5) rot_dpp<0x1B>(zc);   // xor3
    DOT_SLICE(6) rot_dpp<0xB1>(zc);   // xor1
    DOT_SLICE(7)
#undef DOT_SLICE

    float4 av = {a0, a1, a2, a3};
    *(float4*)&part[g][hbase] = av;
    __syncthreads();

    // finisher: all 64 lanes sum half the chunks for one h, combine via xor32
    float s4 = part[half * 4 + 0][myh] + part[half * 4 + 1][myh] +
               part[half * 4 + 2][myh] + part[half * 4 + 3][myh];
    s4 += __shfl_xor(s4, 32);
    if (wlane) {
      float z = tanh_fast(s4 + xw_cur);
      zlast = z;
      zsh[myh] = (f16)z;
    }
    __syncthreads();
    xw_cur = xw_nxt;
  }

  // outputs: z_last (f32, exact from register) + out[b] GEMV
  if (wlane) {
    outp[BATCH + (size_t)b_ * HID + myh] = zlast;
    red[myh] = zlast * Wout[myh];
  }
  __syncthreads();
  if (tid < 64) {
    float s2 = 0.f;
#pragma unroll
    for (int i = 0; i < 8; ++i) s2 += red[tid + 64 * i];
    red[tid] = s2;
  }
  __syncthreads();
  if (tid == 0) {
    float s3 = 0.f;
    for (int i = 0; i < 64; ++i) s3 += red[i];
    outp[b_] = s3 + bout[0];
  }
}

// ---------------------------------------------------------------------------
extern "C" void kernel_launch(void* const* d_in, const int* in_sizes, int n_in,
                              void* d_out, int out_size, void* d_ws, size_t ws_size,
                              hipStream_t stream) {
  const float* x     = (const float*)d_in[0];
  const float* carry = (const float*)d_in[1];
  const float* Wsu   = (const float*)d_in[2];
  const float* bsu   = (const float*)d_in[3];
  const float* Wout  = (const float*)d_in[4];
  const float* bout  = (const float*)d_in[5];
  float* outp = (float*)d_out;

  char* ws = (char*)d_ws;
  f16* WzT = (f16*)(ws);                        // 512 KB
  f16* WxT = (f16*)(ws + 512 * 1024);           // 256 KB
  f16* xw  = (f16*)(ws + 768 * 1024);           // 128 MB (131072*512*2B)

  prep_kernel<<<dim3((768 * 512) / 256), 256, 0, stream>>>(Wsu, WzT, WxT);
  gemm1_kernel<<<dim3(BATCH * SEQ / 64, HID / 64), 256, 0, stream>>>(x, WxT, bsu, xw);
  scan_kernel<<<dim3(BATCH), 1024, 0, stream>>>(WzT, xw, carry, Wout, bout, outp);
}

// Round 8
// 2176.148 us; speedup vs baseline: 3.4424x; 1.0008x over previous
//
#include <hip/hip_runtime.h>
#include <hip/hip_bf16.h>

typedef _Float16 f16;
typedef _Float16 f16x2 __attribute__((ext_vector_type(2)));
typedef _Float16 f16x4 __attribute__((ext_vector_type(4)));
typedef _Float16 f16x8 __attribute__((ext_vector_type(8)));

#define BATCH 128
#define SEQ   1024
#define IND   256
#define HID   512

#if defined(__has_builtin)
#if __has_builtin(__builtin_amdgcn_fdot2)
#define HAVE_FDOT2 1
#endif
#endif

__device__ __forceinline__ float fdot2(f16x2 a, f16x2 b, float c) {
#ifdef HAVE_FDOT2
  return __builtin_amdgcn_fdot2(a, b, c, false);
#else
  return c + (float)a[0] * (float)b[0] + (float)a[1] * (float)b[1];
#endif
}

union v8u {
  f16x8 v;
  f16x2 h[4];
  int   i[4];
};

__device__ __forceinline__ float tanh_fast(float s) {
  float e = __expf(2.0f * s);
  return 1.0f - 2.0f / (e + 1.0f);
}

// cross-lane float move via DPP (quad_perm etc.), all-lanes-active contexts only
template <int CTRL>
__device__ __forceinline__ float fdpp(float x) {
  int i = __builtin_bit_cast(int, x);
  i = __builtin_amdgcn_mov_dpp(i, CTRL, 0xf, 0xf, false);
  return __builtin_bit_cast(float, i);
}

// sum over lane^32 partner using v_permlane32_swap (VALU pipe, no LDS)
__device__ __forceinline__ float xor32_sum(float x) {
  float lo = x, hi = x;
  asm volatile("v_permlane32_swap_b32 %0, %1" : "+v"(lo), "+v"(hi));
  return lo + hi;  // = x[lane&31] + x[(lane&31)+32] (order-agnostic sum)
}

// ---------------------------------------------------------------------------
// prep: W_su f32 [768][512] -> WzT f16 [h=512][k=512], WxT f16 [h=512][d=256]
// ---------------------------------------------------------------------------
__global__ __launch_bounds__(256) void prep_kernel(const float* __restrict__ Wsu,
                                                   f16* __restrict__ WzT,
                                                   f16* __restrict__ WxT) {
  int g = blockIdx.x * 256 + threadIdx.x;  // 0 .. 768*512-1
  int k = g >> 9;
  int h = g & 511;
  float v = Wsu[g];
  if (k < HID) WzT[h * HID + k] = (f16)v;
  else         WxT[h * IND + (k - HID)] = (f16)v;
}

// ---------------------------------------------------------------------------
// gemm1: xw[m][n] = sum_k x[m][k] * WxT[n][k] + bsu[n]   (f16 dot2, 64x64 tile)
// ---------------------------------------------------------------------------
__global__ __launch_bounds__(256) void gemm1_kernel(const float* __restrict__ x,
                                                    const f16* __restrict__ WxT,
                                                    const float* __restrict__ bsu,
                                                    f16* __restrict__ xw) {
  __shared__ __align__(16) f16x2 X2[16][64];  // [k-pair][row]
  __shared__ __align__(16) f16x2 W2[16][64];  // [k-pair][col]
  int m0 = blockIdx.x * 64, n0 = blockIdx.y * 64;
  int tid = threadIdx.x;
  int cg = tid & 15;
  int rg = tid >> 4;
  int sr = tid >> 2;
  int q  = tid & 3;

  float4 bv = *(const float4*)&bsu[n0 + cg * 4];
  float bj[4] = {bv.x, bv.y, bv.z, bv.w};
  float acc[4][4];
#pragma unroll
  for (int i = 0; i < 4; ++i)
#pragma unroll
    for (int j = 0; j < 4; ++j) acc[i][j] = bj[j];

  for (int ks = 0; ks < 8; ++ks) {
    int k0 = ks * 32;
    const float4* xp = (const float4*)&x[(m0 + sr) * IND + k0 + q * 8];
    float4 a0 = xp[0], a1 = xp[1];
    X2[q * 4 + 0][sr] = (f16x2){(f16)a0.x, (f16)a0.y};
    X2[q * 4 + 1][sr] = (f16x2){(f16)a0.z, (f16)a0.w};
    X2[q * 4 + 2][sr] = (f16x2){(f16)a1.x, (f16)a1.y};
    X2[q * 4 + 3][sr] = (f16x2){(f16)a1.z, (f16)a1.w};
    v8u wv;
    wv.v = *(const f16x8*)&WxT[(n0 + sr) * IND + k0 + q * 8];
#pragma unroll
    for (int p = 0; p < 4; ++p) W2[q * 4 + p][sr] = wv.h[p];
    __syncthreads();
#pragma unroll
    for (int kk = 0; kk < 16; ++kk) {
      v8u xv, wvv;
      xv.v = *(const f16x8*)&X2[kk][rg * 4];
      wvv.v = *(const f16x8*)&W2[kk][cg * 4];
#pragma unroll
      for (int i = 0; i < 4; ++i) {
        f16x2 xi = xv.h[i];
#pragma unroll
        for (int j = 0; j < 4; ++j) {
          acc[i][j] = fdot2(xi, wvv.h[j], acc[i][j]);
        }
      }
    }
    __syncthreads();
  }
#pragma unroll
  for (int i = 0; i < 4; ++i) {
    int row = m0 + rg * 4 + i;
    f16x4 o = {(f16)acc[i][0], (f16)acc[i][1], (f16)acc[i][2], (f16)acc[i][3]};
    *(f16x4*)&xw[row * HID + n0 + cg * 4] = o;
  }
}

// ---------------------------------------------------------------------------
// scan v4: 128 blocks (1 batch) x 1024 threads (16 waves, 1 block/CU).
// Lane map: w=tid>>6, l=tid&63; chunk kc = (l&3)|((l>>5)<<2) owns k-chunk
// [kc*64,+64); row-quad hq=(l>>2)&7; rows hbase=w*32+hq*4 .. +3.
// Rows 0..2 register-resident (96 VGPR); row 3 streamed from LDS wl[s][tid].
// z-reads: 8 swizzled broadcast b128 reads (schedule slice s^kc -> banks
// disjoint across lanes). Cross-chunk reduction IN-REGISTER: pack-reduce
// xor1 (quad_perm 0xB1), xor2 (quad_perm 0x4E), xor32 (v_permlane32_swap)
// -- all VALU, no part[] LDS, no extra barrier. Lane l<32 ends with the
// full sum for row w*32+l. zsh double-buffered => ONE barrier per step.
// ---------------------------------------------------------------------------
__global__ __launch_bounds__(1024, 4) void scan_kernel(
    const f16* __restrict__ WzT, const f16* __restrict__ xw,
    const float* __restrict__ carry, const float* __restrict__ Wout,
    const float* __restrict__ bout, float* __restrict__ outp) {
  __shared__ __align__(16) f16 zsh[2][512];        // 2 KB double-buffered z
  __shared__ __align__(16) f16x8 wl[8][1024];      // 128 KB: row-3 weights
  __shared__ float red[512];                       // 2 KB epilogue

  const int b_ = blockIdx.x;
  const int tid = threadIdx.x;
  const int w = tid >> 6, l = tid & 63;
  const int kc = (l & 3) | (((l >> 5) & 1) << 2);  // chunk: lane bits 0,1,5
  const int hq = (l >> 2) & 7;                     // row-quad: lane bits 2,3,4
  const int hbase = w * 32 + hq * 4;

  // rows hbase..hbase+2 -> registers (96 VGPRs), slice-permuted by (s^kc)
  f16x2 wreg[3][32];
#pragma unroll
  for (int r = 0; r < 3; ++r) {
#pragma unroll
    for (int s = 0; s < 8; ++s) {
      v8u v;
      v.v = *(const f16x8*)&WzT[(hbase + r) * HID + kc * 64 + ((s ^ kc) & 7) * 8];
#pragma unroll
      for (int p = 0; p < 4; ++p) wreg[r][s * 4 + p] = v.h[p];
    }
  }
  // opacity pin: prevent remat/sinking of register-resident rows
#pragma unroll
  for (int r = 0; r < 3; ++r) {
#pragma unroll
    for (int s = 0; s < 32; ++s) {
      unsigned u = __builtin_bit_cast(unsigned, wreg[r][s]);
      asm volatile("" : "+v"(u));
      wreg[r][s] = __builtin_bit_cast(f16x2, u);
    }
  }
  // row hbase+3 -> LDS in consumption order
#pragma unroll
  for (int s = 0; s < 8; ++s)
    wl[s][tid] = *(const f16x8*)&WzT[(hbase + 3) * HID + kc * 64 + ((s ^ kc) & 7) * 8];

  // z^0 from carry, plain layout
  if (tid < HID) zsh[0][tid] = (f16)carry[b_ * HID + tid];

  const int myh = w * 32 + (l & 31);
  const bool wlane = (l < 32);
  float xw_cur = 0.f;
  if (wlane) xw_cur = (float)xw[(size_t)b_ * SEQ * HID + myh];

  __syncthreads();

  float zlast = 0.f;
  for (int t = 0; t < SEQ; ++t) {
    const int p = t & 1;
    float xw_nxt = xw_cur;
    if (wlane) {
      int tn = (t + 1 < SEQ) ? t + 1 : t;
      xw_nxt = (float)xw[((size_t)b_ * SEQ + tn) * HID + myh];
    }

    const f16* zb = &zsh[p][kc * 64];
    float a0 = 0.f, a1 = 0.f, a2 = 0.f, a3 = 0.f;
#pragma unroll
    for (int s = 0; s < 8; ++s) {
      v8u zc, wv;
      zc.v = *(const f16x8*)&zb[((s ^ kc) & 7) * 8];  // broadcast, conflict-free
      wv.v = wl[s][tid];
#pragma unroll
      for (int q4 = 0; q4 < 4; ++q4) {
        f16x2 zp = zc.h[q4];
        int pi = s * 4 + q4;
        a0 = fdot2(zp, wreg[0][pi], a0);
        a1 = fdot2(zp, wreg[1][pi], a1);
        a2 = fdot2(zp, wreg[2][pi], a2);
        a3 = fdot2(zp, wv.h[q4], a3);
      }
    }

    // ---- in-register pack-reduce over chunk bits (lane bits 0,1,5) ----
    const bool b0 = (l & 1), b1 = (l & 2);
    // stage xor1 (quad_perm [1,0,3,2] = 0xB1)
    float k01 = b0 ? a1 : a0, s01 = b0 ? a0 : a1;
    float u01 = k01 + fdpp<0xB1>(s01);
    float k23 = b0 ? a3 : a2, s23 = b0 ? a2 : a3;
    float u23 = k23 + fdpp<0xB1>(s23);
    // stage xor2 (quad_perm [2,3,0,1] = 0x4E)
    float kk2 = b1 ? u23 : u01, ss2 = b1 ? u01 : u23;
    float vv = kk2 + fdpp<0x4E>(ss2);
    // stage xor32 (v_permlane32_swap)
    float tot = xor32_sum(vv);
    // lane l (and l^32) now holds full sum for row w*32 + (l&31)

    if (wlane) {
      float z = tanh_fast(tot + xw_cur);
      zlast = z;
      zsh[p ^ 1][myh] = (f16)z;
    }
    __syncthreads();
    xw_cur = xw_nxt;
  }

  // outputs: z_last (f32, exact from register) + out[b] GEMV
  if (wlane) {
    outp[BATCH + (size_t)b_ * HID + myh] = zlast;
    red[myh] = zlast * Wout[myh];
  }
  __syncthreads();
  if (tid < 64) {
    float s2 = 0.f;
#pragma unroll
    for (int i = 0; i < 8; ++i) s2 += red[tid + 64 * i];
    red[tid] = s2;
  }
  __syncthreads();
  if (tid == 0) {
    float s3 = 0.f;
    for (int i = 0; i < 64; ++i) s3 += red[i];
    outp[b_] = s3 + bout[0];
  }
}

// ---------------------------------------------------------------------------
extern "C" void kernel_launch(void* const* d_in, const int* in_sizes, int n_in,
                              void* d_out, int out_size, void* d_ws, size_t ws_size,
                              hipStream_t stream) {
  const float* x     = (const float*)d_in[0];
  const float* carry = (const float*)d_in[1];
  const float* Wsu   = (const float*)d_in[2];
  const float* bsu   = (const float*)d_in[3];
  const float* Wout  = (const float*)d_in[4];
  const float* bout  = (const float*)d_in[5];
  float* outp = (float*)d_out;

  char* ws = (char*)d_ws;
  f16* WzT = (f16*)(ws);                        // 512 KB
  f16* WxT = (f16*)(ws + 512 * 1024);           // 256 KB
  f16* xw  = (f16*)(ws + 768 * 1024);           // 128 MB (131072*512*2B)

  prep_kernel<<<dim3((768 * 512) / 256), 256, 0, stream>>>(Wsu, WzT, WxT);
  gemm1_kernel<<<dim3(BATCH * SEQ / 64, HID / 64), 256, 0, stream>>>(x, WxT, bsu, xw);
  scan_kernel<<<dim3(BATCH), 1024, 0, stream>>>(WzT, xw, carry, Wout, bout, outp);
}

// Round 9
// 1606.671 us; speedup vs baseline: 4.6626x; 1.3544x over previous
//
#include <hip/hip_runtime.h>
#include <hip/hip_bf16.h>

typedef _Float16 f16;
typedef _Float16 f16x2 __attribute__((ext_vector_type(2)));
typedef _Float16 f16x4 __attribute__((ext_vector_type(4)));
typedef _Float16 f16x8 __attribute__((ext_vector_type(8)));

#define BATCH 128
#define SEQ   1024
#define IND   256
#define HID   512

#if defined(__has_builtin)
#if __has_builtin(__builtin_amdgcn_fdot2)
#define HAVE_FDOT2 1
#endif
#endif

__device__ __forceinline__ float fdot2(f16x2 a, f16x2 b, float c) {
#ifdef HAVE_FDOT2
  return __builtin_amdgcn_fdot2(a, b, c, false);
#else
  return c + (float)a[0] * (float)b[0] + (float)a[1] * (float)b[1];
#endif
}

union v8u {
  f16x8 v;
  f16x2 h[4];
};

__device__ __forceinline__ float tanh_fast(float s) {
  float e = __expf(2.0f * s);
  return 1.0f - 2.0f / (e + 1.0f);
}

// cross-lane float move via DPP; all lanes active required
template <int CTRL>
__device__ __forceinline__ float fdpp(float x) {
  int i = __builtin_bit_cast(int, x);
  i = __builtin_amdgcn_mov_dpp(i, CTRL, 0xf, 0xf, false);
  return __builtin_bit_cast(float, i);
}

// ---------------------------------------------------------------------------
// prep: W_su f32 [768][512] -> WzT f16 [h=512][k=512], WxT f16 [h=512][d=256]
// ---------------------------------------------------------------------------
__global__ __launch_bounds__(256) void prep_kernel(const float* __restrict__ Wsu,
                                                   f16* __restrict__ WzT,
                                                   f16* __restrict__ WxT) {
  int g = blockIdx.x * 256 + threadIdx.x;  // 0 .. 768*512-1
  int k = g >> 9;
  int h = g & 511;
  float v = Wsu[g];
  if (k < HID) WzT[h * HID + k] = (f16)v;
  else         WxT[h * IND + (k - HID)] = (f16)v;
}

// ---------------------------------------------------------------------------
// gemm1: xw[m][n] = sum_k x[m][k] * WxT[n][k] + bsu[n]   (f16 dot2, 64x64 tile)
// ---------------------------------------------------------------------------
__global__ __launch_bounds__(256) void gemm1_kernel(const float* __restrict__ x,
                                                    const f16* __restrict__ WxT,
                                                    const float* __restrict__ bsu,
                                                    f16* __restrict__ xw) {
  __shared__ __align__(16) f16x2 X2[16][64];  // [k-pair][row]
  __shared__ __align__(16) f16x2 W2[16][64];  // [k-pair][col]
  int m0 = blockIdx.x * 64, n0 = blockIdx.y * 64;
  int tid = threadIdx.x;
  int cg = tid & 15;
  int rg = tid >> 4;
  int sr = tid >> 2;
  int q  = tid & 3;

  float4 bv = *(const float4*)&bsu[n0 + cg * 4];
  float bj[4] = {bv.x, bv.y, bv.z, bv.w};
  float acc[4][4];
#pragma unroll
  for (int i = 0; i < 4; ++i)
#pragma unroll
    for (int j = 0; j < 4; ++j) acc[i][j] = bj[j];

  for (int ks = 0; ks < 8; ++ks) {
    int k0 = ks * 32;
    const float4* xp = (const float4*)&x[(m0 + sr) * IND + k0 + q * 8];
    float4 a0 = xp[0], a1 = xp[1];
    X2[q * 4 + 0][sr] = (f16x2){(f16)a0.x, (f16)a0.y};
    X2[q * 4 + 1][sr] = (f16x2){(f16)a0.z, (f16)a0.w};
    X2[q * 4 + 2][sr] = (f16x2){(f16)a1.x, (f16)a1.y};
    X2[q * 4 + 3][sr] = (f16x2){(f16)a1.z, (f16)a1.w};
    v8u wv;
    wv.v = *(const f16x8*)&WxT[(n0 + sr) * IND + k0 + q * 8];
#pragma unroll
    for (int p = 0; p < 4; ++p) W2[q * 4 + p][sr] = wv.h[p];
    __syncthreads();
#pragma unroll
    for (int kk = 0; kk < 16; ++kk) {
      v8u xv, wvv;
      xv.v = *(const f16x8*)&X2[kk][rg * 4];
      wvv.v = *(const f16x8*)&W2[kk][cg * 4];
#pragma unroll
      for (int i = 0; i < 4; ++i) {
        f16x2 xi = xv.h[i];
#pragma unroll
        for (int j = 0; j < 4; ++j) {
          acc[i][j] = fdot2(xi, wvv.h[j], acc[i][j]);
        }
      }
    }
    __syncthreads();
  }
#pragma unroll
  for (int i = 0; i < 4; ++i) {
    int row = m0 + rg * 4 + i;
    f16x4 o = {(f16)acc[i][0], (f16)acc[i][1], (f16)acc[i][2], (f16)acc[i][3]};
    *(f16x4*)&xw[row * HID + n0 + cg * 4] = o;
  }
}

// ---------------------------------------------------------------------------
// scan v5: 128 blocks (1 batch) x 512 threads (8 waves, 2/SIMD, 256-reg cap).
// Lane map: w=tid>>6, l=tid&63; kc=l&7 (64-k chunk); hq=l>>3 (row octet);
// thread owns rows hbase=w*64+hq*8 .. +7, k in [kc*64, kc*64+64).
// Rows 0..5 register-resident (192 VGPR); rows 6,7 streamed from LDS
// wl6/wl7[s][tid] (64 KB/step total, conflict-free contiguous b128).
// z-reads: 8 swizzled broadcast b128 (slice (s^kc) -> 32 banks covered).
// Cross-chunk reduce fully in-register, pack at each stage:
//   xor7 (dpp row_half_mirror 0x141) -> xor1 (quad_perm 0xB1) ->
//   xor2 (quad_perm 0x4E); masks {7,1,2} generate Z2^3 => full 8-chunk sum.
// Lane l ends with row hbase + 4*b2+2*b0+b1; ALL 512 lanes tanh+write.
// zsh double-buffered => ONE barrier per step.
// ---------------------------------------------------------------------------
__global__ __launch_bounds__(512, 2) void scan_kernel(
    const f16* __restrict__ WzT, const f16* __restrict__ xw,
    const float* __restrict__ carry, const float* __restrict__ Wout,
    const float* __restrict__ bout, float* __restrict__ outp) {
  __shared__ __align__(16) f16 zsh[2][512];        // 2 KB double-buffered z
  __shared__ __align__(16) f16x8 wl6[8][512];      // 64 KB row-6 weights
  __shared__ __align__(16) f16x8 wl7[8][512];      // 64 KB row-7 weights
  __shared__ float red[512];                       // 2 KB epilogue
  // total ~132 KB -> guarantees 1 block/CU

  const int b_ = blockIdx.x;
  const int tid = threadIdx.x;
  const int w = tid >> 6, l = tid & 63;
  const int kc = l & 7;
  const int hq = l >> 3;
  const int hbase = w * 64 + hq * 8;

  // rows hbase..hbase+5 -> registers (192 VGPRs), slice-permuted by (s^kc)
  f16x2 wreg[6][32];
#pragma unroll
  for (int r = 0; r < 6; ++r) {
#pragma unroll
    for (int s = 0; s < 8; ++s) {
      v8u v;
      v.v = *(const f16x8*)&WzT[(hbase + r) * HID + kc * 64 + ((s ^ kc) & 7) * 8];
#pragma unroll
      for (int p = 0; p < 4; ++p) wreg[r][s * 4 + p] = v.h[p];
    }
  }
  // opacity pin: prevent remat/sinking
#pragma unroll
  for (int r = 0; r < 6; ++r) {
#pragma unroll
    for (int s = 0; s < 32; ++s) {
      unsigned u = __builtin_bit_cast(unsigned, wreg[r][s]);
      asm volatile("" : "+v"(u));
      wreg[r][s] = __builtin_bit_cast(f16x2, u);
    }
  }
  // rows hbase+6, hbase+7 -> LDS in consumption order
#pragma unroll
  for (int s = 0; s < 8; ++s) {
    wl6[s][tid] = *(const f16x8*)&WzT[(hbase + 6) * HID + kc * 64 + ((s ^ kc) & 7) * 8];
    wl7[s][tid] = *(const f16x8*)&WzT[(hbase + 7) * HID + kc * 64 + ((s ^ kc) & 7) * 8];
  }

  // z^0 from carry, plain layout
  zsh[0][tid] = (f16)carry[b_ * HID + tid];

  // output row after pack-reduce: hbase + 4*b2 + 2*b0 + b1
  const int b0 = l & 1, b1 = (l >> 1) & 1, b2 = (l >> 2) & 1;
  const int myh = hbase + (b2 << 2) + (b0 << 1) + b1;

  float xw_cur = (float)xw[(size_t)b_ * SEQ * HID + myh];

  __syncthreads();

  float zlast = 0.f;
  for (int t = 0; t < SEQ; ++t) {
    const int p = t & 1;
    int tn = (t + 1 < SEQ) ? t + 1 : t;
    float xw_nxt = (float)xw[((size_t)b_ * SEQ + tn) * HID + myh];

    const f16* zb = &zsh[p][kc * 64];
    float a0 = 0.f, a1 = 0.f, a2 = 0.f, a3 = 0.f;
    float a4 = 0.f, a5 = 0.f, a6 = 0.f, a7 = 0.f;
#pragma unroll
    for (int s = 0; s < 8; ++s) {
      v8u zc, w6, w7;
      zc.v = *(const f16x8*)&zb[((s ^ kc) & 7) * 8];  // broadcast, bank-spread
      w6.v = wl6[s][tid];
      w7.v = wl7[s][tid];
#pragma unroll
      for (int q4 = 0; q4 < 4; ++q4) {
        f16x2 zp = zc.h[q4];
        int pi = s * 4 + q4;
        a0 = fdot2(zp, wreg[0][pi], a0);
        a1 = fdot2(zp, wreg[1][pi], a1);
        a2 = fdot2(zp, wreg[2][pi], a2);
        a3 = fdot2(zp, wreg[3][pi], a3);
        a4 = fdot2(zp, wreg[4][pi], a4);
        a5 = fdot2(zp, wreg[5][pi], a5);
        a6 = fdot2(zp, w6.h[q4], a6);
        a7 = fdot2(zp, w7.h[q4], a7);
      }
    }

    // ---- in-register pack-reduce over kc (lane bits 0,1,2) ----
    // stage xor7 (dpp 0x141 = row_half_mirror), keep-select by b2
    float n0_ = b2 ? a4 : a0, s0_ = b2 ? a0 : a4;
    float n1_ = b2 ? a5 : a1, s1_ = b2 ? a1 : a5;
    float n2_ = b2 ? a6 : a2, s2_ = b2 ? a2 : a6;
    float n3_ = b2 ? a7 : a3, s3_ = b2 ? a3 : a7;
    n0_ += fdpp<0x141>(s0_);
    n1_ += fdpp<0x141>(s1_);
    n2_ += fdpp<0x141>(s2_);
    n3_ += fdpp<0x141>(s3_);
    // stage xor1 (quad_perm [1,0,3,2] = 0xB1), keep-select by b0
    float m0_ = b0 ? n2_ : n0_, t0_ = b0 ? n0_ : n2_;
    float m1_ = b0 ? n3_ : n1_, t1_ = b0 ? n1_ : n3_;
    m0_ += fdpp<0xB1>(t0_);
    m1_ += fdpp<0xB1>(t1_);
    // stage xor2 (quad_perm [2,3,0,1] = 0x4E), keep-select by b1
    float f0_ = b1 ? m1_ : m0_, g0_ = b1 ? m0_ : m1_;
    float tot = f0_ + fdpp<0x4E>(g0_);
    // lane holds full sum for row myh

    float z = tanh_fast(tot + xw_cur);
    zlast = z;
    zsh[p ^ 1][myh] = (f16)z;
    __syncthreads();
    xw_cur = xw_nxt;
  }

  // outputs: z_last (f32, exact from register) + out[b] GEMV
  outp[BATCH + (size_t)b_ * HID + myh] = zlast;
  red[myh] = zlast * Wout[myh];
  __syncthreads();
  if (tid < 64) {
    float s2 = 0.f;
#pragma unroll
    for (int i = 0; i < 8; ++i) s2 += red[tid + 64 * i];
    red[tid] = s2;
  }
  __syncthreads();
  if (tid == 0) {
    float s3 = 0.f;
    for (int i = 0; i < 64; ++i) s3 += red[i];
    outp[b_] = s3 + bout[0];
  }
}

// ---------------------------------------------------------------------------
extern "C" void kernel_launch(void* const* d_in, const int* in_sizes, int n_in,
                              void* d_out, int out_size, void* d_ws, size_t ws_size,
                              hipStream_t stream) {
  const float* x     = (const float*)d_in[0];
  const float* carry = (const float*)d_in[1];
  const float* Wsu   = (const float*)d_in[2];
  const float* bsu   = (const float*)d_in[3];
  const float* Wout  = (const float*)d_in[4];
  const float* bout  = (const float*)d_in[5];
  float* outp = (float*)d_out;

  char* ws = (char*)d_ws;
  f16* WzT = (f16*)(ws);                        // 512 KB
  f16* WxT = (f16*)(ws + 512 * 1024);           // 256 KB
  f16* xw  = (f16*)(ws + 768 * 1024);           // 128 MB (131072*512*2B)

  prep_kernel<<<dim3((768 * 512) / 256), 256, 0, stream>>>(Wsu, WzT, WxT);
  gemm1_kernel<<<dim3(BATCH * SEQ / 64, HID / 64), 256, 0, stream>>>(x, WxT, bsu, xw);
  scan_kernel<<<dim3(BATCH), 512, 0, stream>>>(WzT, xw, carry, Wout, bout, outp);
}